// Round 2
// baseline (222.999 us; speedup 1.0000x reference)
//
#include <hip/hip_runtime.h>

// TAM fused kernel round 2: pool -> G(softmax kern) + L(sigmoid gate) ->
// gated depthwise temporal conv -> transposed write.
// C=12, T=10, H*W=28, K=3. n = in_sizes[0]/3360.
//
// Round-2 changes vs round-1 (215.6 us, 4.1 TB/s):
//  - G branch spread across 240 threads (z in LDS) -> short critical path,
//    no z[20] per-thread array -> VGPR down, __launch_bounds__(256,8).
//  - sx staged in OUTPUT order [t][c][s]: phase-5 reads/stores identity-indexed.
//  - nontemporal load/store on the 440MB x / 440MB out streams.
//  - float4 pooling.

#define CC 12
#define TT 10
#define HWS 28
#define KK 3
#define CT (CC*TT)            // 120
#define SAMPLE (CC*TT*HWS)    // 3360 floats per sample
#define SAMPLE4 (SAMPLE/4)    // 840 float4
#define CHW4 (CC*HWS/4)       // 84 float4 per t-slice
#define HW4 (HWS/4)           // 7 float4 per (c)
#define EPSF 1e-5f

typedef float f4 __attribute__((ext_vector_type(4)));

__global__ __launch_bounds__(256, 8) void tam_kernel(
    const float* __restrict__ x,
    const float* __restrict__ w_g1,
    const float* __restrict__ g1_gamma, const float* __restrict__ g1_beta,
    const float* __restrict__ g1_mean,  const float* __restrict__ g1_var,
    const float* __restrict__ w_g2,
    const float* __restrict__ w_l1,
    const float* __restrict__ l1_gamma, const float* __restrict__ l1_beta,
    const float* __restrict__ l1_mean,  const float* __restrict__ l1_var,
    const float* __restrict__ w_l2,
    float* __restrict__ out)
{
    __shared__ float sx[SAMPLE];     // x in OUTPUT order: [t][c][s]
    __shared__ float spool[CT];      // pooled[c][t]
    __shared__ float sz[CC * 2 * TT];// G hidden z[c][j], 240
    __shared__ float skern[CC * KK]; // softmax kernel per (c,k)
    __shared__ float sa1[3 * TT];    // L-branch hidden [m][t]
    __shared__ float sact[CT];       // sigmoid gate per (c,t)

    const int n   = blockIdx.x;
    const int tid = threadIdx.x;

    // ---- phase 1: stage sample into LDS, transposed to [t][c][s] ----
    const f4* xg  = reinterpret_cast<const f4*>(x + (size_t)n * SAMPLE);
    f4* sx4 = reinterpret_cast<f4*>(sx);
    for (int v = tid; v < SAMPLE4; v += 256) {
        const int c   = v / (TT * HW4);          // 0..11
        const int rem = v % (TT * HW4);          // 0..69
        const int t   = rem / HW4;               // 0..9
        const int i   = rem % HW4;               // 0..6
        const f4 val = __builtin_nontemporal_load(xg + v);
        sx4[t * CHW4 + c * HW4 + i] = val;
    }
    __syncthreads();

    // ---- phase 2: spatial mean -> pooled[c][t] (120 threads, f4) ----
    if (tid < CT) {
        const int c = tid / TT, t = tid % TT;
        const f4* row = sx4 + t * CHW4 + c * HW4;
        f4 a = row[0];
        #pragma unroll
        for (int i = 1; i < HW4; ++i) { const f4 b = row[i]; a.x+=b.x; a.y+=b.y; a.z+=b.z; a.w+=b.w; }
        spool[tid] = (a.x + a.y + a.z + a.w) * (1.0f / 28.0f);
    }
    __syncthreads();

    // ---- phase 3: t0-239: G hidden z[c][j]; t240-255: L conv1 -> sa1 ----
    if (tid < CC * 2 * TT) {                     // 240 threads
        const int c = tid / (2 * TT), j = tid % (2 * TT);
        float s = 0.f;
        #pragma unroll
        for (int t = 0; t < TT; ++t) s += spool[c * TT + t] * w_g1[j * TT + t];
        s = (s - g1_mean[j]) * rsqrtf(g1_var[j] + EPSF) * g1_gamma[j] + g1_beta[j];
        sz[tid] = fmaxf(s, 0.f);
    } else {                                     // 16 threads -> 30 entries (2 each)
        const int idx2 = tid - CC * 2 * TT;      // 0..15
        #pragma unroll
        for (int q = 0; q < 2; ++q) {
            const int e = idx2 * 2 + q;
            if (e < 3 * TT) {
                const int m = e / TT, t = e % TT;
                float s = 0.f;
                #pragma unroll
                for (int c = 0; c < CC; ++c) {
                    #pragma unroll
                    for (int k = 0; k < KK; ++k) {
                        const int t2 = t + k - 1;
                        if (t2 >= 0 && t2 < TT)
                            s += spool[c * TT + t2] * w_l1[(m * CC + c) * KK + k];
                    }
                }
                s = (s - l1_mean[m]) * rsqrtf(l1_var[m] + EPSF) * l1_gamma[m] + l1_beta[m];
                sa1[e] = fmaxf(s, 0.f);
            }
        }
    }
    __syncthreads();

    // ---- phase 4: t0-11: G scores+softmax; t64-183: L conv2+sigmoid ----
    if (tid < CC) {
        const int c = tid;
        float sc0 = 0.f, sc1 = 0.f, sc2 = 0.f;
        #pragma unroll
        for (int j = 0; j < 2 * TT; ++j) {
            const float zj = sz[c * 2 * TT + j];
            sc0 += zj * w_g2[0 * 2 * TT + j];
            sc1 += zj * w_g2[1 * 2 * TT + j];
            sc2 += zj * w_g2[2 * 2 * TT + j];
        }
        const float m = fmaxf(sc0, fmaxf(sc1, sc2));
        const float e0 = __expf(sc0 - m), e1 = __expf(sc1 - m), e2 = __expf(sc2 - m);
        const float r = 1.0f / (e0 + e1 + e2);
        skern[c * KK + 0] = e0 * r;
        skern[c * KK + 1] = e1 * r;
        skern[c * KK + 2] = e2 * r;
    }
    if (tid >= 64 && tid < 64 + CT) {
        const int idx = tid - 64;
        const int c = idx / TT, t = idx % TT;
        float s = 0.f;
        #pragma unroll
        for (int m = 0; m < 3; ++m) s += sa1[m * TT + t] * w_l2[c * 3 + m];
        sact[idx] = 1.0f / (1.0f + __expf(-s));
    }
    __syncthreads();

    // ---- phase 5: gated temporal conv, identity-indexed write ----
    // out[n*SAMPLE + v] with v = t*CHW4 + c*HW4 + i  (f4 units)
    f4* og4 = reinterpret_cast<f4*>(out + (size_t)n * SAMPLE);
    for (int v = tid; v < SAMPLE4; v += 256) {
        const int t   = v / CHW4;                // 0..9
        const int c   = (v % CHW4) / HW4;        // 0..11
        const float k0 = skern[c * KK + 0];
        const float k1 = skern[c * KK + 1];
        const float k2 = skern[c * KK + 2];
        f4 acc = (f4)0.f;
        if (t > 0) {
            const float a = sact[c * TT + (t - 1)] * k0;
            const f4 xv = sx4[v - CHW4];
            acc += a * xv;
        }
        {
            const float a = sact[c * TT + t] * k1;
            const f4 xv = sx4[v];
            acc += a * xv;
        }
        if (t < TT - 1) {
            const float a = sact[c * TT + (t + 1)] * k2;
            const f4 xv = sx4[v + CHW4];
            acc += a * xv;
        }
        __builtin_nontemporal_store(acc, og4 + v);
    }
}

extern "C" void kernel_launch(void* const* d_in, const int* in_sizes, int n_in,
                              void* d_out, int out_size, void* d_ws, size_t ws_size,
                              hipStream_t stream) {
    (void)n_in; (void)out_size; (void)d_ws; (void)ws_size;
    const float* x        = (const float*)d_in[0];
    const float* w_g1     = (const float*)d_in[1];
    const float* g1_gamma = (const float*)d_in[2];
    const float* g1_beta  = (const float*)d_in[3];
    const float* g1_mean  = (const float*)d_in[4];
    const float* g1_var   = (const float*)d_in[5];
    const float* w_g2     = (const float*)d_in[6];
    const float* w_l1     = (const float*)d_in[7];
    const float* l1_gamma = (const float*)d_in[8];
    const float* l1_beta  = (const float*)d_in[9];
    const float* l1_mean  = (const float*)d_in[10];
    const float* l1_var   = (const float*)d_in[11];
    const float* w_l2     = (const float*)d_in[12];
    float* out = (float*)d_out;

    const int n_total = in_sizes[0] / SAMPLE;  // 32768
    tam_kernel<<<n_total, 256, 0, stream>>>(
        x, w_g1, g1_gamma, g1_beta, g1_mean, g1_var, w_g2,
        w_l1, l1_gamma, l1_beta, l1_mean, l1_var, w_l2, out);
}